// Round 2
// baseline (130.772 us; speedup 1.0000x reference)
//
#include <hip/hip_runtime.h>
#include <hip/hip_bf16.h>

// Problem: bmm [16,256,512] @ [16,512,2048] -> [16,256,2048], fp32 in/out.
#define NB 16
#define ND 256
#define NK 512
#define NT 2048

// Tile: BM=128, BN=64, BK=32. 256 threads = 4 waves (2x2 wave grid),
// wave tile 64x32 = 4x2 MFMAs of 16x16x32 bf16. grid = (32,2,16) = 1024
// blocks = 4 blocks/CU (vs 2 before) for latency hiding.
#define BM 128
#define BN 64
#define BK 32
#define RSA 40   // A LDS row stride (bf16): 80 B, 16B-aligned b128 reads
#define RSB 36   // B LDS row stride (bf16): 72 B, 8B-aligned b64, <=4-way banks
#define KITERS (NK / BK)   // 16

typedef __attribute__((ext_vector_type(8))) short short8;
typedef __attribute__((ext_vector_type(4))) float f32x4;

union S8U { short8 v; uint2 u[2]; };
union BF2U { __hip_bfloat162 h; unsigned int u; };

__device__ inline unsigned int pack2bf(float a, float b) {
    BF2U c; c.h = __float22bfloat162_rn(make_float2(a, b));
    return c.u;
}

__global__ __launch_bounds__(256, 4)  // cap VGPR<=128 -> 4 blocks/CU
void bmm_bf16_mfma(const float* __restrict__ x, const float* __restrict__ path,
                   float* __restrict__ out) {
    const int n0 = blockIdx.x * BN;
    const int m0 = blockIdx.y * BM;
    const int b  = blockIdx.z;
    const int t    = threadIdx.x;
    const int lane = t & 63;
    const int wv   = t >> 6;          // wave id 0..3
    const int wr   = (wv >> 1) * 64;  // wave row offset (0/64)
    const int wc   = (wv & 1) * 32;   // wave col offset (0/32)
    const int q    = lane >> 4;       // quad 0..3
    const int lm   = lane & 15;

    // double-buffered LDS
    __shared__ unsigned short As[2][BM * RSA]; // [m][k] bf16
    __shared__ unsigned short Bs[2][BN * RSB]; // [n][k] bf16 (transposed)

    const float* xg = x    + ((size_t)b * ND + m0) * NK;
    const float* pg = path + (size_t)b * NK * NT + n0;

    f32x4 acc[4][2];
#pragma unroll
    for (int i = 0; i < 4; ++i)
#pragma unroll
        for (int j = 0; j < 2; ++j)
            acc[i][j] = (f32x4){0.f, 0.f, 0.f, 0.f};

    // ---- prefetch registers
    float4 aReg[4];
    float  bReg[8];

    // A: 128x32 fp32 = 1024 float4; thread does 4. row = f>>3, c4 = f&7.
    // B: 32x64 fp32; wave wv owns k-rows wv*8..wv*8+7, lane owns col n0+lane.
#define LOAD_TILE(k0)                                                         \
    {                                                                         \
        _Pragma("unroll")                                                     \
        for (int i = 0; i < 4; ++i) {                                         \
            int f = t + i * 256;                                              \
            int row = f >> 3, c4 = f & 7;                                     \
            aReg[i] = *reinterpret_cast<const float4*>(                       \
                xg + (size_t)row * NK + (k0) + c4 * 4);                       \
        }                                                                     \
        _Pragma("unroll")                                                     \
        for (int j = 0; j < 8; ++j)                                           \
            bReg[j] = pg[(size_t)((k0) + wv * 8 + j) * NT + lane];            \
    }

#define STORE_TILE(buf)                                                       \
    {                                                                         \
        _Pragma("unroll")                                                     \
        for (int i = 0; i < 4; ++i) {                                         \
            int f = t + i * 256;                                              \
            int row = f >> 3, c4 = f & 7;                                     \
            uint2 p;                                                          \
            p.x = pack2bf(aReg[i].x, aReg[i].y);                              \
            p.y = pack2bf(aReg[i].z, aReg[i].w);                              \
            *reinterpret_cast<uint2*>(&As[buf][row * RSA + c4 * 4]) = p;      \
        }                                                                     \
        uint2 pk0, pk1;                                                       \
        pk0.x = pack2bf(bReg[0], bReg[1]);                                    \
        pk0.y = pack2bf(bReg[2], bReg[3]);                                    \
        pk1.x = pack2bf(bReg[4], bReg[5]);                                    \
        pk1.y = pack2bf(bReg[6], bReg[7]);                                    \
        *reinterpret_cast<uint2*>(&Bs[buf][lane * RSB + wv * 8]) = pk0;       \
        *reinterpret_cast<uint2*>(&Bs[buf][lane * RSB + wv * 8 + 4]) = pk1;   \
    }

    LOAD_TILE(0)
    STORE_TILE(0)
    __syncthreads();

    for (int it = 0; it < KITERS; ++it) {
        const int cur = it & 1;
        // issue next tile's global loads early (overlap with MFMA below)
        if (it + 1 < KITERS) LOAD_TILE((it + 1) * BK)

        // fragments from current buffer
        short8 af[4];
        short8 bfr[2];
#pragma unroll
        for (int mt = 0; mt < 4; ++mt) {
            int row = wr + mt * 16 + lm;
            af[mt] = *reinterpret_cast<const short8*>(&As[cur][row * RSA + q * 8]);
        }
#pragma unroll
        for (int nt = 0; nt < 2; ++nt) {
            int n = wc + nt * 16 + lm;
            S8U s;
            s.u[0] = *reinterpret_cast<const uint2*>(&Bs[cur][n * RSB + q * 8]);
            s.u[1] = *reinterpret_cast<const uint2*>(&Bs[cur][n * RSB + q * 8 + 4]);
            bfr[nt] = s.v;
        }
#pragma unroll
        for (int mt = 0; mt < 4; ++mt)
#pragma unroll
            for (int nt = 0; nt < 2; ++nt)
                acc[mt][nt] = __builtin_amdgcn_mfma_f32_16x16x32_bf16(
                    af[mt], bfr[nt], acc[mt][nt], 0, 0, 0);

        // convert+store next tile into the other buffer (waits vmcnt here,
        // after MFMA has been issued)
        if (it + 1 < KITERS) STORE_TILE(1 - cur)
        __syncthreads();
    }

    // epilogue: C/D layout col=lane&15, row=(lane>>4)*4+reg  [m89-verified]
    float* og = out + ((size_t)b * ND + m0 + wr) * NT + n0 + wc;
#pragma unroll
    for (int mt = 0; mt < 4; ++mt) {
#pragma unroll
        for (int r = 0; r < 4; ++r) {
            int row = mt * 16 + q * 4 + r;
#pragma unroll
            for (int nt = 0; nt < 2; ++nt) {
                int col = nt * 16 + lm;
                og[(size_t)row * NT + col] = acc[mt][nt][r];
            }
        }
    }
}

extern "C" void kernel_launch(void* const* d_in, const int* in_sizes, int n_in,
                              void* d_out, int out_size, void* d_ws, size_t ws_size,
                              hipStream_t stream) {
    const float* x    = (const float*)d_in[0];   // [16, 256, 512]
    const float* path = (const float*)d_in[1];   // [16, 512, 2048]
    float* out        = (float*)d_out;           // [16, 256, 2048]
    dim3 grid(NT / BN, ND / BM, NB);             // (32, 2, 16) = 1024 blocks
    dim3 block(256);
    bmm_bf16_mfma<<<grid, block, 0, stream>>>(x, path, out);
}

// Round 3
// 125.462 us; speedup vs baseline: 1.0423x; 1.0423x over previous
//
#include <hip/hip_runtime.h>
#include <hip/hip_bf16.h>

// Problem: bmm [16,256,512] @ [16,512,2048] -> [16,256,2048], fp32 in/out.
#define NB 16
#define ND 256
#define NK 512
#define NT 2048

// Tile: BM=128, BN=64, BK=32. 256 threads = 4 waves (2x2), wave tile 64x32 =
// 4x2 MFMAs of 16x16x32 bf16. grid = (32,2,16) = 1024 blocks -> 4/CU.
// Depth-2 global prefetch: LDS store consumes registers loaded TWO tiles ago;
// the 12 loads of the next tile stay in flight across the store's vmcnt wait.
#define BM 128
#define BN 64
#define BK 32
#define RSA 40   // A LDS row stride (bf16): 80 B, 16B-aligned b128 reads
#define RSB 36   // B LDS row stride (bf16): 72 B
#define KITERS (NK / BK)   // 16

typedef __attribute__((ext_vector_type(8))) short short8;
typedef __attribute__((ext_vector_type(4))) float f32x4;

union S8U { short8 v; uint2 u[2]; };
union BF2U { __hip_bfloat162 h; unsigned int u; };

__device__ inline unsigned int pack2bf(float a, float b) {
    BF2U c; c.h = __float22bfloat162_rn(make_float2(a, b));
    return c.u;
}

__global__ __launch_bounds__(256, 4)  // 4 blocks/CU; VGPR cap 128 (est ~120 live)
void bmm_bf16_mfma(const float* __restrict__ x, const float* __restrict__ path,
                   float* __restrict__ out) {
    const int n0 = blockIdx.x * BN;
    const int m0 = blockIdx.y * BM;
    const int b  = blockIdx.z;
    const int t    = threadIdx.x;
    const int lane = t & 63;
    const int wv   = t >> 6;
    const int wr   = (wv >> 1) * 64;  // wave row offset (0/64)
    const int wc   = (wv & 1) * 32;   // wave col offset (0/32)
    const int q    = lane >> 4;
    const int lm   = lane & 15;

    __shared__ unsigned short As[2][BM * RSA];
    __shared__ unsigned short Bs[2][BN * RSB];

    const float* xg = x    + ((size_t)b * ND + m0) * NK;
    const float* pg = path + (size_t)b * NK * NT + n0;

    f32x4 acc[4][2];
#pragma unroll
    for (int i = 0; i < 4; ++i)
#pragma unroll
        for (int j = 0; j < 2; ++j)
            acc[i][j] = (f32x4){0.f, 0.f, 0.f, 0.f};

    // two prefetch register sets (depth-2)
    float4 aReg[2][4];
    float  bReg[2][8];

#define LOAD_TILE(s, k0)                                                      \
    {                                                                         \
        _Pragma("unroll")                                                     \
        for (int i = 0; i < 4; ++i) {                                         \
            int f = t + i * 256;                                              \
            int row = f >> 3, c4 = f & 7;                                     \
            aReg[s][i] = *reinterpret_cast<const float4*>(                    \
                xg + (size_t)row * NK + (k0) + c4 * 4);                       \
        }                                                                     \
        _Pragma("unroll")                                                     \
        for (int j = 0; j < 8; ++j)                                           \
            bReg[s][j] = pg[(size_t)((k0) + wv * 8 + j) * NT + lane];         \
    }

#define STORE_TILE(s, buf)                                                    \
    {                                                                         \
        _Pragma("unroll")                                                     \
        for (int i = 0; i < 4; ++i) {                                         \
            int f = t + i * 256;                                              \
            int row = f >> 3, c4 = f & 7;                                     \
            uint2 p;                                                          \
            p.x = pack2bf(aReg[s][i].x, aReg[s][i].y);                        \
            p.y = pack2bf(aReg[s][i].z, aReg[s][i].w);                        \
            *reinterpret_cast<uint2*>(&As[buf][row * RSA + c4 * 4]) = p;      \
        }                                                                     \
        uint2 pk0, pk1;                                                       \
        pk0.x = pack2bf(bReg[s][0], bReg[s][1]);                              \
        pk0.y = pack2bf(bReg[s][2], bReg[s][3]);                              \
        pk1.x = pack2bf(bReg[s][4], bReg[s][5]);                              \
        pk1.y = pack2bf(bReg[s][6], bReg[s][7]);                              \
        *reinterpret_cast<uint2*>(&Bs[buf][lane * RSB + wv * 8]) = pk0;       \
        *reinterpret_cast<uint2*>(&Bs[buf][lane * RSB + wv * 8 + 4]) = pk1;   \
    }

    // prologue: tiles 0 and 1 in flight; store tile0 (leaves tile1's 12 loads
    // outstanding -> compiler waits vmcnt(12), not vmcnt(0))
    LOAD_TILE(0, 0)
    LOAD_TILE(1, BK)
    STORE_TILE(0, 0)
    __syncthreads();

    for (int it = 0; it < KITERS; ++it) {
        const int cur = it & 1;

        // issue tile it+2 into the regset freed two iterations ago
        if (it + 2 < KITERS) LOAD_TILE(cur, (it + 2) * BK)

        // fragments + MFMA from current buffer
        short8 af[4];
        short8 bfr[2];
#pragma unroll
        for (int mt = 0; mt < 4; ++mt) {
            int row = wr + mt * 16 + lm;
            af[mt] = *reinterpret_cast<const short8*>(&As[cur][row * RSA + q * 8]);
        }
#pragma unroll
        for (int nt = 0; nt < 2; ++nt) {
            int n = wc + nt * 16 + lm;
            S8U s;
            s.u[0] = *reinterpret_cast<const uint2*>(&Bs[cur][n * RSB + q * 8]);
            s.u[1] = *reinterpret_cast<const uint2*>(&Bs[cur][n * RSB + q * 8 + 4]);
            bfr[nt] = s.v;
        }
#pragma unroll
        for (int mt = 0; mt < 4; ++mt)
#pragma unroll
            for (int nt = 0; nt < 2; ++nt)
                acc[mt][nt] = __builtin_amdgcn_mfma_f32_16x16x32_bf16(
                    af[mt], bfr[nt], acc[mt][nt], 0, 0, 0);

        // store tile it+1 (loaded one iteration ago; tile it+2's loads stay
        // in flight across this wait)
        if (it + 1 < KITERS) STORE_TILE(1 - cur, 1 - cur)
        __syncthreads();
    }

    // epilogue: C/D layout col=lane&15, row=(lane>>4)*4+reg  [m89-verified]
    float* og = out + ((size_t)b * ND + m0 + wr) * NT + n0 + wc;
#pragma unroll
    for (int mt = 0; mt < 4; ++mt) {
#pragma unroll
        for (int r = 0; r < 4; ++r) {
            int row = mt * 16 + q * 4 + r;
#pragma unroll
            for (int nt = 0; nt < 2; ++nt) {
                int col = nt * 16 + lm;
                og[(size_t)row * NT + col] = acc[mt][nt][r];
            }
        }
    }
}

extern "C" void kernel_launch(void* const* d_in, const int* in_sizes, int n_in,
                              void* d_out, int out_size, void* d_ws, size_t ws_size,
                              hipStream_t stream) {
    const float* x    = (const float*)d_in[0];   // [16, 256, 512]
    const float* path = (const float*)d_in[1];   // [16, 512, 2048]
    float* out        = (float*)d_out;           // [16, 256, 2048]
    dim3 grid(NT / BN, ND / BM, NB);             // (32, 2, 16) = 1024 blocks
    dim3 block(256);
    bmm_bf16_mfma<<<grid, block, 0, stream>>>(x, path, out);
}